// Round 2
// baseline (361.099 us; speedup 1.0000x reference)
//
#include <hip/hip_runtime.h>

#define TS 20        // states
#define TT 400       // T*T
#define NB 128       // batch
#define NL 512       // seq len
#define HALF 256     // fwd/bwd split point
#define S_START 17
#define S_END 18
#define DEPTH 6      // prefetch distance (ring has 8 slots)
#define LOG2E 1.4426950408889634f
#define LN2 0.6931471805599453f

// ws float-index layout:
//  [0]          gold energy accumulator (atomic, memset to 0)
//  [16..144)    fwd s per batch
//  [160..2720)  fwd lq per batch*20
//  [2720..2848) bwd s
//  [2848..5408) bwd lq
#define WS_GOLD 0
#define WS_FS 16
#define WS_FL 160
#define WS_BS 2720
#define WS_BL 2848

#define AS1C(p) ((const __attribute__((address_space(1))) unsigned int*)(p))
#define AS3(p)  ((__attribute__((address_space(3))) unsigned int*)(p))

__device__ __forceinline__ float rfl_f(float x) {
    return __int_as_float(__builtin_amdgcn_readfirstlane(__float_as_int(x)));
}

// issue one raw tile (1600 B) into an LDS ring slot: 2 global_load_lds ops
__device__ __forceinline__ void issue_tile(const float* __restrict__ tr, int row,
                                           int b, int lane, float* slot) {
    const char* g = (const char*)(tr + (size_t)(row * NB + b) * TT);
    __builtin_amdgcn_global_load_lds(AS1C(g + lane * 16), AS3(slot), 16, 0, 0);
    if (lane < 36)
        __builtin_amdgcn_global_load_lds(AS1C(g + 1024 + lane * 16), AS3(slot + 256), 16, 0, 0);
}

// raw ring slot -> exp2(x*log2e + costL2) -> chain buf (raw element order)
__device__ __forceinline__ void stage(const float* __restrict__ src,
                                      float* __restrict__ dst, int lane,
                                      const float* cA, const float* cB) {
    float4 a = *(const float4*)(src + 4 * lane);
    float4 ea;
    ea.x = __builtin_amdgcn_exp2f(fmaf(a.x, LOG2E, cA[0]));
    ea.y = __builtin_amdgcn_exp2f(fmaf(a.y, LOG2E, cA[1]));
    ea.z = __builtin_amdgcn_exp2f(fmaf(a.z, LOG2E, cA[2]));
    ea.w = __builtin_amdgcn_exp2f(fmaf(a.w, LOG2E, cA[3]));
    *(float4*)(dst + 4 * lane) = ea;
    if (lane < 36) {
        float4 bb = *(const float4*)(src + 256 + 4 * lane);
        float4 eb;
        eb.x = __builtin_amdgcn_exp2f(fmaf(bb.x, LOG2E, cB[0]));
        eb.y = __builtin_amdgcn_exp2f(fmaf(bb.y, LOG2E, cB[1]));
        eb.z = __builtin_amdgcn_exp2f(fmaf(bb.z, LOG2E, cB[2]));
        eb.w = __builtin_amdgcn_exp2f(fmaf(bb.w, LOG2E, cB[3]));
        *(float4*)(dst + 256 + 4 * lane) = eb;
    }
}

// --- main scan: 256 blocks = 128 batches x {fwd,bwd}, 1 wave each -----------
__global__ __launch_bounds__(64) void crf_chain(const float* __restrict__ tr,
                                                const unsigned char* __restrict__ mask8,
                                                const int* __restrict__ mask32,
                                                const int* __restrict__ gold32,
                                                float* __restrict__ wsf) {
    __shared__ float ring[8 * TT];     // raw tiles
    __shared__ float cbuf[2][TT];      // exp'd tiles (raw element order)
    __shared__ int golds[NL];

    const int lane = threadIdx.x;
    const int b = blockIdx.x >> 1;
    const int dir = blockIdx.x & 1;    // 0 = forward, 1 = backward

    // ---- dtype detect (wave-uniform, cheap)
    const bool isu8 = (mask8[1] == 1);   // mask row 0 all-true; byte1==1 iff u8
    int o = 0;
    #pragma unroll
    for (int k = 1; k < 32; k += 2) o |= gold32[k];
    const bool is64 = (o == 0);          // odd words all zero iff int64

    // ---- sequence length from mask column b (monotone per column)
    int cnt = 0;
    #pragma unroll
    for (int t = 0; t < 8; ++t) {
        int l = lane + 64 * t;
        cnt += isu8 ? (mask8[(size_t)l * NB + b] ? 1 : 0)
                    : (mask32[(size_t)l * NB + b] ? 1 : 0);
    }
    #pragma unroll
    for (int off = 1; off < 64; off <<= 1) cnt += __shfl_xor(cnt, off);
    const int len = max(1, min(cnt, NL));

    // ---- gold column -> LDS
    #pragma unroll
    for (int t = 0; t < 8; ++t) {
        int l = lane + 64 * t;
        int g = is64 ? gold32[2 * ((size_t)l * NB + b)] : gold32[(size_t)l * NB + b];
        golds[l] = max(0, min(g, TT - 1));
    }

    // ---- state init
    const int jc = (lane < TS) ? lane : (TS - 1);
    float s, q;
    if (dir == 0) {
        float t0 = tr[(size_t)b * TT + S_START * TS + jc];  // row 0, from=START
        float ref = rfl_f(t0);
        s = ref; q = __expf(t0 - ref);
    } else {
        s = 0.0f; q = (jc == S_END) ? 1.0f : 0.0f;
    }
    float qs[TS];
    #pragma unroll
    for (int i = 0; i < TS; ++i)
        qs[i] = __int_as_float(__builtin_amdgcn_readlane(__float_as_int(q), i));

    // ---- per-lane staging constants (cost in log2 space, on "to" state j = n%20)
    float cA[4], cB[4];
    #pragma unroll
    for (int c = 0; c < 4; ++c) {
        int nA = 4 * lane + c;
        int nB = 256 + 4 * lane + c;
        cA[c] = ((nA % TS) < 4) ? LOG2E : 0.0f;
        cB[c] = ((nB % TS) < 4) ? LOG2E : 0.0f;
    }

    const int S = (dir == 0) ? (min(len, HALF) - 1) : max(len - HALF, 0);
    float e_gold = 0.0f;

    if (S > 0) {
        // tile t corresponds to trellis row: fwd 1+t, bwd len-1-t
        #define LROW(t) ((dir == 0) ? (1 + (t)) : (len - 1 - (t)))
        // prologue: issue tiles 0..DEPTH-1
        #pragma unroll
        for (int d = 0; d < DEPTH; ++d)
            issue_tile(tr, LROW(min(d, S - 1)), b, lane, &ring[d * TT]);
        asm volatile("s_waitcnt vmcnt(10)" ::: "memory");
        __builtin_amdgcn_sched_barrier(0);
        stage(&ring[0], &cbuf[0][0], lane, cA, cB);
        e_gold += ring[golds[LROW(0)]];           // uniform broadcast read

        for (int u = 0; u < S; ++u) {
            // chain reads for this step (cbuf[u&1], staged last step)
            float w[TS];
            if (dir == 0) {
                #pragma unroll
                for (int i = 0; i < TS; ++i) w[i] = cbuf[u & 1][i * TS + jc];
            } else {
                const float4* rp = (const float4*)(&cbuf[u & 1][jc * TS]);
                float4 r0 = rp[0], r1 = rp[1], r2 = rp[2], r3 = rp[3], r4 = rp[4];
                w[0]=r0.x; w[1]=r0.y; w[2]=r0.z; w[3]=r0.w;
                w[4]=r1.x; w[5]=r1.y; w[6]=r1.z; w[7]=r1.w;
                w[8]=r2.x; w[9]=r2.y; w[10]=r2.z; w[11]=r2.w;
                w[12]=r3.x; w[13]=r3.y; w[14]=r3.z; w[15]=r3.w;
                w[16]=r4.x; w[17]=r4.y; w[18]=r4.z; w[19]=r4.w;
            }

            // prefetch tile u+DEPTH (always 2 ops: row clamped -> uniform vmcnt)
            issue_tile(tr, LROW(min(u + DEPTH, S - 1)), b, lane,
                       &ring[((u + DEPTH) & 7) * TT]);
            asm volatile("s_waitcnt vmcnt(10)" ::: "memory");  // tile u+1 landed
            __builtin_amdgcn_sched_barrier(0);

            // stage tile u+1 for next step + gold probe
            int t1 = u + 1;
            if (t1 < S) {
                const float* slot = &ring[(t1 & 7) * TT];
                stage(slot, &cbuf[t1 & 1][0], lane, cA, cB);
                e_gold += slot[golds[LROW(t1)]];
            }

            // dependent matvec: fwd acc_j = sum_i q_i W[i][j]; bwd acc_i = sum_j W[i][j] q_j
            float a0 = qs[0] * w[0];
            float a1 = qs[1] * w[1];
            float a2 = qs[2] * w[2];
            float a3 = qs[3] * w[3];
            a0 = fmaf(qs[4],  w[4],  a0);  a1 = fmaf(qs[5],  w[5],  a1);
            a2 = fmaf(qs[6],  w[6],  a2);  a3 = fmaf(qs[7],  w[7],  a3);
            a0 = fmaf(qs[8],  w[8],  a0);  a1 = fmaf(qs[9],  w[9],  a1);
            a2 = fmaf(qs[10], w[10], a2);  a3 = fmaf(qs[11], w[11], a3);
            a0 = fmaf(qs[12], w[12], a0);  a1 = fmaf(qs[13], w[13], a1);
            a2 = fmaf(qs[14], w[14], a2);  a3 = fmaf(qs[15], w[15], a3);
            a0 = fmaf(qs[16], w[16], a0);  a1 = fmaf(qs[17], w[17], a1);
            a2 = fmaf(qs[18], w[18], a2);  a3 = fmaf(qs[19], w[19], a3);
            float acc = (a0 + a1) + (a2 + a3);

            // exponent-only renormalization off lane 0
            int ebits = __builtin_amdgcn_readfirstlane(__float_as_int(acc));
            int e = ((ebits >> 23) & 255) - 127;
            s += (float)e * LN2;
            q = acc * __int_as_float((127 - e) << 23);   // * 2^-e exactly
            #pragma unroll
            for (int i = 0; i < TS; ++i)
                qs[i] = __int_as_float(__builtin_amdgcn_readlane(__float_as_int(q), i));
        }
        #undef LROW
    }

    float lq = __logf(q);

    // fwd block also owns the row-0 gold energy (mask[0] always true)
    if (dir == 0) e_gold += tr[(size_t)b * TT + golds[0]];

    float* ss = wsf + ((dir == 0) ? WS_FS : WS_BS);
    float* ll = wsf + ((dir == 0) ? WS_FL : WS_BL);
    if (lane == 0) {
        ss[b] = s;
        atomicAdd(wsf + WS_GOLD, e_gold);
    }
    if (lane < TS) ll[b * TS + lane] = lq;
}

// --- merge fwd x bwd, subtract gold, write loss ------------------------------
__global__ __launch_bounds__(128) void crf_merge(const float* __restrict__ wsf,
                                                 float* __restrict__ out) {
    const int b = threadIdx.x;   // 128 threads = 128 batches
    const float* fl = wsf + WS_FL + b * TS;
    const float* bl = wsf + WS_BL + b * TS;
    float v[TS];
    float m = -3e38f;
    #pragma unroll
    for (int i = 0; i < TS; ++i) { v[i] = fl[i] + bl[i]; m = fmaxf(m, v[i]); }
    float sum = 0.0f;
    #pragma unroll
    for (int i = 0; i < TS; ++i) sum += __expf(v[i] - m);
    float part = wsf[WS_FS + b] + wsf[WS_BS + b] + m + __logf(sum);
    #pragma unroll
    for (int off = 32; off; off >>= 1) part += __shfl_down(part, off);
    __shared__ float ps[2];
    if ((threadIdx.x & 63) == 0) ps[threadIdx.x >> 6] = part;
    __syncthreads();
    if (threadIdx.x == 0) out[0] = (ps[0] + ps[1] - wsf[WS_GOLD]) / 128.0f;
}

extern "C" void kernel_launch(void* const* d_in, const int* in_sizes, int n_in,
                              void* d_out, int out_size, void* d_ws, size_t ws_size,
                              hipStream_t stream) {
    const float* tr = (const float*)d_in[0];
    const int* gold32 = (const int*)d_in[1];
    const unsigned char* mask8 = (const unsigned char*)d_in[2];
    const int* mask32 = (const int*)d_in[2];
    float* wsf = (float*)d_ws;
    float* out = (float*)d_out;

    hipMemsetAsync(d_ws, 0, 64, stream);   // zero gold accumulator
    crf_chain<<<256, 64, 0, stream>>>(tr, mask8, mask32, gold32, wsf);
    crf_merge<<<1, 128, 0, stream>>>(wsf, out);
}

// Round 3
// 327.890 us; speedup vs baseline: 1.1013x; 1.1013x over previous
//
#include <hip/hip_runtime.h>

#define TS 20        // states
#define TT 400       // T*T
#define NB 128       // batch
#define NL 512       // seq len
#define HALF 256     // fwd/bwd split point
#define S_START 17
#define S_END 18
#define CSTRIDE 21   // cbuf row stride: coprime with 32 -> conflict-free chain reads
#define LOG2E 1.4426950408889634f
#define LN2 0.6931471805599453f

// ws float-index layout:
//  [0]          gold energy accumulator (atomic, memset to 0)
//  [16..144)    fwd s per batch
//  [160..2720)  fwd lq per batch*20
//  [2720..2848) bwd s
//  [2848..5408) bwd lq
#define WS_GOLD 0
#define WS_FS 16
#define WS_FL 160
#define WS_BS 2720
#define WS_BL 2848

__device__ __forceinline__ float rfl_f(float x) {
    return __int_as_float(__builtin_amdgcn_readfirstlane(__float_as_int(x)));
}

__device__ __forceinline__ void load_tile(const float* __restrict__ tr, int row,
                                          int b, int lane, float4& A, float4& B) {
    const float4* tp = (const float4*)(tr + (size_t)(row * NB + b) * TT);
    A = tp[lane];                      // elements 4*lane .. 4*lane+3 (<256)
    if (lane < 36) B = tp[64 + lane];  // elements 256 .. 399
}

// --- main kernel: blocks 0..255 = chains (128 batches x {fwd,bwd}),
//                  blocks 256..511 = gold gather (concurrent) ----------------
__global__ __launch_bounds__(64, 1) void crf_chain(const float* __restrict__ tr,
                                                   const unsigned char* __restrict__ mask8,
                                                   const int* __restrict__ mask32,
                                                   const int* __restrict__ gold32,
                                                   float* __restrict__ wsf) {
    const int lane = threadIdx.x;

    // ---- dtype detect (wave-uniform, cheap scalar loads)
    const bool isu8 = (mask8[1] == 1);   // mask row 0 all-true; byte1==1 iff u8
    int o = 0;
    #pragma unroll
    for (int k = 1; k < 32; k += 2) o |= gold32[k];
    const bool is64 = (o == 0);          // odd words all zero iff int64

    // =================== gold-gather blocks ===================
    if (blockIdx.x >= 256) {
        const int gb = blockIdx.x - 256;
        float v = 0.0f;
        #pragma unroll
        for (int t = 0; t < 4; ++t) {
            int idx = gb * 256 + t * 64 + lane;   // l*128+b, < 65536
            int m = isu8 ? (int)mask8[idx] : mask32[idx];
            if (m) {
                int g = is64 ? gold32[2 * idx] : gold32[idx];
                g = max(0, min(g, TT - 1));
                v += tr[(size_t)idx * TT + g];
            }
        }
        #pragma unroll
        for (int off = 32; off; off >>= 1) v += __shfl_down(v, off);
        if (lane == 0) atomicAdd(wsf + WS_GOLD, v);
        return;
    }

    // =================== chain blocks ===================
    __shared__ float cbuf[2][TS * CSTRIDE];   // exp'd tiles, reader-major, stride 21

    const int b = blockIdx.x >> 1;
    const int dir = blockIdx.x & 1;    // 0 = forward, 1 = backward

    // ---- sequence length from mask column b (monotone per column)
    int cnt = 0;
    #pragma unroll
    for (int t = 0; t < 8; ++t) {
        size_t l = lane + 64 * t;
        cnt += isu8 ? (mask8[l * NB + b] ? 1 : 0) : (mask32[l * NB + b] ? 1 : 0);
    }
    #pragma unroll
    for (int off = 1; off < 64; off <<= 1) cnt += __shfl_xor(cnt, off);
    const int len = max(1, min(cnt, NL));

    // ---- state init
    const int jc = (lane < TS) ? lane : (TS - 1);
    float s, q;
    if (dir == 0) {
        float t0 = tr[(size_t)b * TT + S_START * TS + jc];  // row 0, from=START
        float ref = rfl_f(t0);
        s = ref; q = __expf(t0 - ref);
    } else {
        s = 0.0f; q = (jc == S_END) ? 1.0f : 0.0f;
    }
    float qs[TS];
    #pragma unroll
    for (int i = 0; i < TS; ++i)
        qs[i] = __int_as_float(__builtin_amdgcn_readlane(__float_as_int(q), i));

    // ---- per-lane staging constants: dst offsets + cost (log2 space)
    // element n: i=n/20 (from), j=n%20 (to); fwd stores transposed (reader = to-state),
    // bwd stores raw (reader = from-state). cost applies on "to" state j<4.
    int dA[4], dB[4];
    float cA[4], cB[4];
    #pragma unroll
    for (int c = 0; c < 4; ++c) {
        int nA = 4 * lane + c;
        int iA = nA / TS, jA = nA - iA * TS;
        dA[c] = (dir == 0) ? (jA * CSTRIDE + iA) : (iA * CSTRIDE + jA);
        cA[c] = (jA < 4) ? LOG2E : 0.0f;
        int nB = 256 + 4 * lane + c;
        int iB = nB / TS, jB = nB - iB * TS;
        dB[c] = (dir == 0) ? (jB * CSTRIDE + iB) : (iB * CSTRIDE + jB);
        cB[c] = (jB < 4) ? LOG2E : 0.0f;
    }

    #define STAGE_TILE(dst, A, B)                                              \
        do {                                                                   \
            (dst)[dA[0]] = __builtin_amdgcn_exp2f(fmaf((A).x, LOG2E, cA[0]));  \
            (dst)[dA[1]] = __builtin_amdgcn_exp2f(fmaf((A).y, LOG2E, cA[1]));  \
            (dst)[dA[2]] = __builtin_amdgcn_exp2f(fmaf((A).z, LOG2E, cA[2]));  \
            (dst)[dA[3]] = __builtin_amdgcn_exp2f(fmaf((A).w, LOG2E, cA[3]));  \
            if (lane < 36) {                                                   \
                (dst)[dB[0]] = __builtin_amdgcn_exp2f(fmaf((B).x, LOG2E, cB[0])); \
                (dst)[dB[1]] = __builtin_amdgcn_exp2f(fmaf((B).y, LOG2E, cB[1])); \
                (dst)[dB[2]] = __builtin_amdgcn_exp2f(fmaf((B).z, LOG2E, cB[2])); \
                (dst)[dB[3]] = __builtin_amdgcn_exp2f(fmaf((B).w, LOG2E, cB[3])); \
            }                                                                  \
        } while (0)

    const int S = (dir == 0) ? (min(len, HALF) - 1) : max(len - HALF, 0);

    if (S > 0) {
        // tile t <-> trellis row: fwd 1+t, bwd len-1-t
        #define LROW(t) ((dir == 0) ? (1 + (t)) : (len - 1 - (t)))
        float4 zz = make_float4(0, 0, 0, 0);
        float4 A0 = zz, B0 = zz, A1 = zz, B1 = zz, A2 = zz, B2 = zz;
        float4 A3 = zz, B3 = zz, A4 = zz, B4 = zz, A5 = zz, B5 = zz;
        load_tile(tr, LROW(0), b, lane, A0, B0);
        if (S > 1) load_tile(tr, LROW(1), b, lane, A1, B1);
        if (S > 2) load_tile(tr, LROW(2), b, lane, A2, B2);
        if (S > 3) load_tile(tr, LROW(3), b, lane, A3, B3);
        if (S > 4) load_tile(tr, LROW(4), b, lane, A4, B4);
        if (S > 5) load_tile(tr, LROW(5), b, lane, A5, B5);
        STAGE_TILE(&cbuf[0][0], A0, B0);

        #define STEP(u, LA, LB, SA, SB)                                        \
            if ((u) < S) {                                                     \
                if ((u) + 6 < S) load_tile(tr, LROW((u) + 6), b, lane, LA, LB);\
                /* chain reads for this step (staged last step) */             \
                const float* rowp = &cbuf[(u) & 1][jc * CSTRIDE];              \
                float w[TS];                                                   \
                _Pragma("unroll")                                              \
                for (int i = 0; i < TS; ++i) w[i] = rowp[i];                   \
                /* stage tile u+1 for next step (independent of w) */          \
                if ((u) + 1 < S) STAGE_TILE(&cbuf[((u) + 1) & 1][0], SA, SB);  \
                /* dependent matvec */                                         \
                float a0 = qs[0] * w[0];                                       \
                float a1 = qs[1] * w[1];                                       \
                float a2 = qs[2] * w[2];                                       \
                float a3 = qs[3] * w[3];                                       \
                a0 = fmaf(qs[4],  w[4],  a0);  a1 = fmaf(qs[5],  w[5],  a1);   \
                a2 = fmaf(qs[6],  w[6],  a2);  a3 = fmaf(qs[7],  w[7],  a3);   \
                a0 = fmaf(qs[8],  w[8],  a0);  a1 = fmaf(qs[9],  w[9],  a1);   \
                a2 = fmaf(qs[10], w[10], a2);  a3 = fmaf(qs[11], w[11], a3);   \
                a0 = fmaf(qs[12], w[12], a0);  a1 = fmaf(qs[13], w[13], a1);   \
                a2 = fmaf(qs[14], w[14], a2);  a3 = fmaf(qs[15], w[15], a3);   \
                a0 = fmaf(qs[16], w[16], a0);  a1 = fmaf(qs[17], w[17], a1);   \
                a2 = fmaf(qs[18], w[18], a2);  a3 = fmaf(qs[19], w[19], a3);   \
                float acc = (a0 + a1) + (a2 + a3);                             \
                /* exponent-only renormalization off lane 0 */                 \
                int ebits = __builtin_amdgcn_readfirstlane(__float_as_int(acc));\
                int e = ((ebits >> 23) & 255) - 127;                           \
                s += (float)e * LN2;                                           \
                q = acc * __int_as_float((127 - e) << 23);                     \
                _Pragma("unroll")                                              \
                for (int i = 0; i < TS; ++i)                                   \
                    qs[i] = __int_as_float(                                    \
                        __builtin_amdgcn_readlane(__float_as_int(q), i));      \
            }

        for (int t = 0; t < S; t += 6) {
            STEP(t + 0, A0, B0, A1, B1);
            STEP(t + 1, A1, B1, A2, B2);
            STEP(t + 2, A2, B2, A3, B3);
            STEP(t + 3, A3, B3, A4, B4);
            STEP(t + 4, A4, B4, A5, B5);
            STEP(t + 5, A5, B5, A0, B0);
        }
        #undef STEP
        #undef LROW
    }

    float lq = __logf(q);

    float* ss = wsf + ((dir == 0) ? WS_FS : WS_BS);
    float* ll = wsf + ((dir == 0) ? WS_FL : WS_BL);
    if (lane == 0) ss[b] = s;
    if (lane < TS) ll[b * TS + lane] = lq;
}

// --- merge fwd x bwd, subtract gold, write loss ------------------------------
__global__ __launch_bounds__(128) void crf_merge(const float* __restrict__ wsf,
                                                 float* __restrict__ out) {
    const int b = threadIdx.x;   // 128 threads = 128 batches
    const float* fl = wsf + WS_FL + b * TS;
    const float* bl = wsf + WS_BL + b * TS;
    float v[TS];
    float m = -3e38f;
    #pragma unroll
    for (int i = 0; i < TS; ++i) { v[i] = fl[i] + bl[i]; m = fmaxf(m, v[i]); }
    float sum = 0.0f;
    #pragma unroll
    for (int i = 0; i < TS; ++i) sum += __expf(v[i] - m);
    float part = wsf[WS_FS + b] + wsf[WS_BS + b] + m + __logf(sum);
    #pragma unroll
    for (int off = 32; off; off >>= 1) part += __shfl_down(part, off);
    __shared__ float ps[2];
    if ((threadIdx.x & 63) == 0) ps[threadIdx.x >> 6] = part;
    __syncthreads();
    if (threadIdx.x == 0) out[0] = (ps[0] + ps[1] - wsf[WS_GOLD]) / 128.0f;
}

extern "C" void kernel_launch(void* const* d_in, const int* in_sizes, int n_in,
                              void* d_out, int out_size, void* d_ws, size_t ws_size,
                              hipStream_t stream) {
    const float* tr = (const float*)d_in[0];
    const int* gold32 = (const int*)d_in[1];
    const unsigned char* mask8 = (const unsigned char*)d_in[2];
    const int* mask32 = (const int*)d_in[2];
    float* wsf = (float*)d_ws;
    float* out = (float*)d_out;

    hipMemsetAsync(d_ws, 0, 64, stream);   // zero gold accumulator
    crf_chain<<<512, 64, 0, stream>>>(tr, mask8, mask32, gold32, wsf);
    crf_merge<<<1, 128, 0, stream>>>(wsf, out);
}

// Round 4
// 207.063 us; speedup vs baseline: 1.7439x; 1.5835x over previous
//
#include <hip/hip_runtime.h>

#define TS 20        // states
#define TT 400       // T*T
#define NB 128       // batch
#define NL 512       // seq len
#define HALF 256     // fwd/bwd split point
#define S_START 17
#define S_END 18
#define CSTRIDE 21   // cbuf row stride: coprime with 32 -> conflict-free chain reads
#define CBWORDS 536  // 20*21 = 420 data + 112 dump (lanes 36..63) + pad
#define LSTRIDE (NB * TT)   // floats between consecutive trellis rows, fixed b
#define LOG2E 1.4426950408889634f
#define LN2 0.6931471805599453f

// ws float-index layout:
//  [0]          gold energy accumulator (atomic, memset to 0)
//  [16..144)    fwd s per batch
//  [160..2720)  fwd lq per batch*20
//  [2720..2848) bwd s
//  [2848..5408) bwd lq
#define WS_GOLD 0
#define WS_FS 16
#define WS_FL 160
#define WS_BS 2720
#define WS_BL 2848

__device__ __forceinline__ float rfl_f(float x) {
    return __int_as_float(__builtin_amdgcn_readfirstlane(__float_as_int(x)));
}

// --- main kernel: blocks 0..255 = chains (128 batches x {fwd,bwd}),
//                  blocks 256..511 = gold gather (concurrent) ----------------
__global__ __launch_bounds__(64, 1) void crf_chain(const float* __restrict__ tr,
                                                   const unsigned char* __restrict__ mask8,
                                                   const int* __restrict__ mask32,
                                                   const int* __restrict__ gold32,
                                                   float* __restrict__ wsf) {
    const int lane = threadIdx.x;

    // ---- dtype detect (wave-uniform)
    const bool isu8 = (mask8[1] == 1);   // mask row 0 all-true; byte1==1 iff u8
    int o = 0;
    #pragma unroll
    for (int k = 1; k < 32; k += 2) o |= gold32[k];
    const bool is64 = (o == 0);          // odd words all zero iff int64

    // =================== gold-gather blocks ===================
    if (blockIdx.x >= 256) {
        const int gb = blockIdx.x - 256;
        float v = 0.0f;
        #pragma unroll
        for (int t = 0; t < 4; ++t) {
            int idx = gb * 256 + t * 64 + lane;   // l*128+b, < 65536
            int m = isu8 ? (int)mask8[idx] : mask32[idx];
            if (m) {
                int g = is64 ? gold32[2 * idx] : gold32[idx];
                g = max(0, min(g, TT - 1));
                v += tr[(size_t)idx * TT + g];
            }
        }
        #pragma unroll
        for (int off = 32; off; off >>= 1) v += __shfl_down(v, off);
        if (lane == 0) atomicAdd(wsf + WS_GOLD, v);
        return;
    }

    // =================== chain blocks ===================
    __shared__ float cbuf[2][CBWORDS];   // exp'd tiles, reader-major

    const int b = blockIdx.x >> 1;
    const int dir = blockIdx.x & 1;    // 0 = forward, 1 = backward
    const float* trb = tr + (size_t)b * TT;

    // ---- sequence length from mask column b (monotone per column)
    int cnt = 0;
    #pragma unroll
    for (int t = 0; t < 8; ++t) {
        size_t l = lane + 64 * t;
        cnt += isu8 ? (mask8[l * NB + b] ? 1 : 0) : (mask32[l * NB + b] ? 1 : 0);
    }
    #pragma unroll
    for (int off = 1; off < 64; off <<= 1) cnt += __shfl_xor(cnt, off);
    const int len = max(1, min(cnt, NL));

    // ---- state init
    const int jc = (lane < TS) ? lane : (TS - 1);
    const int jcs = jc * CSTRIDE;
    float s, q;
    if (dir == 0) {
        float t0 = trb[S_START * TS + jc];      // row 0, from=START
        float ref = rfl_f(t0);
        s = ref; q = __expf(t0 - ref);
    } else {
        s = 0.0f; q = (jc == S_END) ? 1.0f : 0.0f;
    }
    float qs[TS];
    #pragma unroll
    for (int i = 0; i < TS; ++i)
        qs[i] = __int_as_float(__builtin_amdgcn_readlane(__float_as_int(q), i));

    // ---- per-lane staging constants: dst offsets + cost (log2 space)
    // element n: i=n/20 (from), j=n%20 (to); fwd stores transposed (reader = to-state),
    // bwd raw (reader = from-state). cost on "to" j<4. lanes>=36 B-part -> dump.
    const int fB = min(64 + lane, 99);   // B-half float4 index (clamped)
    int dA[4], dB[4];
    float cA[4], cB[4];
    #pragma unroll
    for (int c = 0; c < 4; ++c) {
        int nA = 4 * lane + c;                       // < 256
        int iA = nA / TS, jA = nA - iA * TS;
        dA[c] = (dir == 0) ? (jA * CSTRIDE + iA) : (iA * CSTRIDE + jA);
        cA[c] = (jA < 4) ? LOG2E : 0.0f;
        if (lane < 36) {
            int nB = 256 + 4 * lane + c;             // < 400
            int iB = nB / TS, jB = nB - iB * TS;
            dB[c] = (dir == 0) ? (jB * CSTRIDE + iB) : (iB * CSTRIDE + jB);
            cB[c] = (jB < 4) ? LOG2E : 0.0f;
        } else {
            dB[c] = 420 + (lane - 36) * 4 + c;       // private dump slot
            cB[c] = 0.0f;
        }
    }

    #define STAGE_TILE(dst, A, B)                                              \
        do {                                                                   \
            (dst)[dA[0]] = __builtin_amdgcn_exp2f(fmaf((A).x, LOG2E, cA[0]));  \
            (dst)[dA[1]] = __builtin_amdgcn_exp2f(fmaf((A).y, LOG2E, cA[1]));  \
            (dst)[dA[2]] = __builtin_amdgcn_exp2f(fmaf((A).z, LOG2E, cA[2]));  \
            (dst)[dA[3]] = __builtin_amdgcn_exp2f(fmaf((A).w, LOG2E, cA[3]));  \
            (dst)[dB[0]] = __builtin_amdgcn_exp2f(fmaf((B).x, LOG2E, cB[0])); \
            (dst)[dB[1]] = __builtin_amdgcn_exp2f(fmaf((B).y, LOG2E, cB[1])); \
            (dst)[dB[2]] = __builtin_amdgcn_exp2f(fmaf((B).z, LOG2E, cB[2])); \
            (dst)[dB[3]] = __builtin_amdgcn_exp2f(fmaf((B).w, LOG2E, cB[3])); \
        } while (0)

    const int S = (dir == 0) ? (min(len, HALF) - 1) : max(len - HALF, 0);

    if (S > 0) {
        // tile t <-> trellis row: fwd 1+t, bwd len-1-t
        #define LROW(t) ((dir == 0) ? (1 + (t)) : (len - 1 - (t)))
        float4 A0, B0, A1, B1, A2, B2, A3, B3, A4, B4, A5, B5;
        #define LOAD_TILE(t, A, B)                                             \
            do {                                                               \
                int row_ = LROW(min((t), S - 1));                              \
                const float4* tp_ = (const float4*)(trb + (size_t)row_ * LSTRIDE); \
                A = tp_[lane];                                                 \
                B = tp_[fB];                                                   \
            } while (0)
        LOAD_TILE(0, A0, B0);
        LOAD_TILE(1, A1, B1);
        LOAD_TILE(2, A2, B2);
        LOAD_TILE(3, A3, B3);
        LOAD_TILE(4, A4, B4);
        LOAD_TILE(5, A5, B5);
        STAGE_TILE(&cbuf[0][0], A0, B0);

        // ---- single-basic-block step: no branches, predicated state update
        #define STEP(U, LA, LB, SA, SB, RB, WB)                                \
        {                                                                      \
            LOAD_TILE((U) + 6, LA, LB);              /* prefetch, clamped */   \
            float w[TS];                                                       \
            _Pragma("unroll")                                                  \
            for (int i = 0; i < TS; ++i) w[i] = cbuf[RB][jcs + i];             \
            STAGE_TILE(&cbuf[WB][0], SA, SB);        /* stage tile U+1 */      \
            float a0 = qs[0] * w[0];                                           \
            float a1 = qs[1] * w[1];                                           \
            float a2 = qs[2] * w[2];                                           \
            float a3 = qs[3] * w[3];                                           \
            a0 = fmaf(qs[4],  w[4],  a0);  a1 = fmaf(qs[5],  w[5],  a1);       \
            a2 = fmaf(qs[6],  w[6],  a2);  a3 = fmaf(qs[7],  w[7],  a3);       \
            a0 = fmaf(qs[8],  w[8],  a0);  a1 = fmaf(qs[9],  w[9],  a1);       \
            a2 = fmaf(qs[10], w[10], a2);  a3 = fmaf(qs[11], w[11], a3);       \
            a0 = fmaf(qs[12], w[12], a0);  a1 = fmaf(qs[13], w[13], a1);       \
            a2 = fmaf(qs[14], w[14], a2);  a3 = fmaf(qs[15], w[15], a3);       \
            a0 = fmaf(qs[16], w[16], a0);  a1 = fmaf(qs[17], w[17], a1);       \
            a2 = fmaf(qs[18], w[18], a2);  a3 = fmaf(qs[19], w[19], a3);       \
            float acc = (a0 + a1) + (a2 + a3);                                 \
            int ebits = __builtin_amdgcn_readfirstlane(__float_as_int(acc));   \
            int e = ((ebits >> 23) & 255) - 127;                               \
            bool live = (U) < S;                                               \
            s = live ? fmaf((float)e, LN2, s) : s;                             \
            q = live ? (acc * __int_as_float((127 - e) << 23)) : q;            \
            _Pragma("unroll")                                                  \
            for (int i = 0; i < TS; ++i)                                       \
                qs[i] = __int_as_float(                                        \
                    __builtin_amdgcn_readlane(__float_as_int(q), i));          \
        }

        const int nsteps = ((S + 5) / 6) * 6;
        for (int u = 0; u < nsteps; u += 6) {
            STEP(u + 0, A0, B0, A1, B1, 0, 1);
            STEP(u + 1, A1, B1, A2, B2, 1, 0);
            STEP(u + 2, A2, B2, A3, B3, 0, 1);
            STEP(u + 3, A3, B3, A4, B4, 1, 0);
            STEP(u + 4, A4, B4, A5, B5, 0, 1);
            STEP(u + 5, A5, B5, A0, B0, 1, 0);
        }
        #undef STEP
        #undef LOAD_TILE
        #undef LROW
    }

    float lq = __logf(q);

    float* ss = wsf + ((dir == 0) ? WS_FS : WS_BS);
    float* ll = wsf + ((dir == 0) ? WS_FL : WS_BL);
    if (lane == 0) ss[b] = s;
    if (lane < TS) ll[b * TS + lane] = lq;
}

// --- merge fwd x bwd, subtract gold, write loss ------------------------------
__global__ __launch_bounds__(128) void crf_merge(const float* __restrict__ wsf,
                                                 float* __restrict__ out) {
    const int b = threadIdx.x;   // 128 threads = 128 batches
    const float* fl = wsf + WS_FL + b * TS;
    const float* bl = wsf + WS_BL + b * TS;
    float v[TS];
    float m = -3e38f;
    #pragma unroll
    for (int i = 0; i < TS; ++i) { v[i] = fl[i] + bl[i]; m = fmaxf(m, v[i]); }
    float sum = 0.0f;
    #pragma unroll
    for (int i = 0; i < TS; ++i) sum += __expf(v[i] - m);
    float part = wsf[WS_FS + b] + wsf[WS_BS + b] + m + __logf(sum);
    #pragma unroll
    for (int off = 32; off; off >>= 1) part += __shfl_down(part, off);
    __shared__ float ps[2];
    if ((threadIdx.x & 63) == 0) ps[threadIdx.x >> 6] = part;
    __syncthreads();
    if (threadIdx.x == 0) out[0] = (ps[0] + ps[1] - wsf[WS_GOLD]) / 128.0f;
}

extern "C" void kernel_launch(void* const* d_in, const int* in_sizes, int n_in,
                              void* d_out, int out_size, void* d_ws, size_t ws_size,
                              hipStream_t stream) {
    const float* tr = (const float*)d_in[0];
    const int* gold32 = (const int*)d_in[1];
    const unsigned char* mask8 = (const unsigned char*)d_in[2];
    const int* mask32 = (const int*)d_in[2];
    float* wsf = (float*)d_ws;
    float* out = (float*)d_out;

    hipMemsetAsync(d_ws, 0, 64, stream);   // zero gold accumulator
    crf_chain<<<512, 64, 0, stream>>>(tr, mask8, mask32, gold32, wsf);
    crf_merge<<<1, 128, 0, stream>>>(wsf, out);
}

// Round 5
// 195.750 us; speedup vs baseline: 1.8447x; 1.0578x over previous
//
#include <hip/hip_runtime.h>

#define TS 20        // states
#define TT 400       // T*T
#define NB 128       // batch
#define NL 512       // seq len
#define HALF 256     // fwd/bwd split point
#define S_START 17
#define S_END 18
#define CSTRIDE 36   // cbuf row stride (words): rows 16B-aligned for ds_read_b128
#define CBWORDS 832  // 20*36 = 720 data + 112 dump (lanes 36..63)
#define LSTRIDE (NB * TT)   // floats between consecutive trellis rows, fixed b
#define LOG2E 1.4426950408889634f
#define LN2 0.6931471805599453f

// ws float-index layout:
//  [0]          gold energy accumulator (atomic, memset to 0)
//  [16..144)    fwd s per batch
//  [160..2720)  fwd lq per batch*20
//  [2720..2848) bwd s
//  [2848..5408) bwd lq
#define WS_GOLD 0
#define WS_FS 16
#define WS_FL 160
#define WS_BS 2720
#define WS_BL 2848

typedef float f32x4 __attribute__((ext_vector_type(4)));
struct W5 { f32x4 r0, r1, r2, r3, r4; };

__device__ __forceinline__ float rfl_f(float x) {
    return __int_as_float(__builtin_amdgcn_readfirstlane(__float_as_int(x)));
}

// --- main kernel: blocks 0..255 = chains (128 batches x {fwd,bwd}),
//                  blocks 256..511 = gold gather (concurrent) ----------------
__global__ __launch_bounds__(64, 1) void crf_chain(const float* __restrict__ tr,
                                                   const unsigned char* __restrict__ mask8,
                                                   const int* __restrict__ mask32,
                                                   const int* __restrict__ gold32,
                                                   float* __restrict__ wsf) {
    const int lane = threadIdx.x;

    // ---- dtype detect (wave-uniform)
    const bool isu8 = (mask8[1] == 1);   // mask row 0 all-true; byte1==1 iff u8
    int o = 0;
    #pragma unroll
    for (int k = 1; k < 32; k += 2) o |= gold32[k];
    const bool is64 = (o == 0);          // odd words all zero iff int64

    // =================== gold-gather blocks ===================
    if (blockIdx.x >= 256) {
        const int gb = blockIdx.x - 256;
        float v = 0.0f;
        #pragma unroll
        for (int t = 0; t < 4; ++t) {
            int idx = gb * 256 + t * 64 + lane;   // l*128+b, < 65536
            int m = isu8 ? (int)mask8[idx] : mask32[idx];
            if (m) {
                int g = is64 ? gold32[2 * idx] : gold32[idx];
                g = max(0, min(g, TT - 1));
                v += tr[(size_t)idx * TT + g];
            }
        }
        #pragma unroll
        for (int off = 32; off; off >>= 1) v += __shfl_down(v, off);
        if (lane == 0) atomicAdd(wsf + WS_GOLD, v);
        return;
    }

    // =================== chain blocks ===================
    __shared__ float cbuf[2][CBWORDS];   // exp'd tiles, reader-major

    const int b = blockIdx.x >> 1;
    const int dir = blockIdx.x & 1;    // 0 = forward, 1 = backward
    const float* trb = tr + (size_t)b * TT;

    // ---- sequence length from mask column b (monotone per column)
    int cnt = 0;
    #pragma unroll
    for (int t = 0; t < 8; ++t) {
        size_t l = lane + 64 * t;
        cnt += isu8 ? (mask8[l * NB + b] ? 1 : 0) : (mask32[l * NB + b] ? 1 : 0);
    }
    #pragma unroll
    for (int off = 1; off < 64; off <<= 1) cnt += __shfl_xor(cnt, off);
    const int len = max(1, min(cnt, NL));

    // ---- state init
    const int jc = (lane < TS) ? lane : (TS - 1);
    const int jcs = jc * CSTRIDE;
    float s, q;
    if (dir == 0) {
        float t0 = trb[S_START * TS + jc];      // row 0, from=START (no cost at l=0)
        float ref = rfl_f(t0);
        s = ref; q = __expf(t0 - ref);
    } else {
        s = 0.0f; q = (jc == S_END) ? 1.0f : 0.0f;
    }
    float qs[TS];
    #pragma unroll
    for (int i = 0; i < TS; ++i)
        qs[i] = __int_as_float(__builtin_amdgcn_readlane(__float_as_int(q), i));

    // ---- per-lane staging constants: dst offsets + cost (log2 space)
    // element n: i=n/20 (from), j=n%20 (to); fwd stores transposed (reader = to-state),
    // bwd raw (reader = from-state). cost on "to" j<4. lanes>=36 B-part -> dump.
    const int fB = min(64 + lane, 99);   // B-half float4 index (clamped)
    int dA[4], dB[4];
    float cA[4], cB[4];
    #pragma unroll
    for (int c = 0; c < 4; ++c) {
        int nA = 4 * lane + c;                       // < 256
        int iA = nA / TS, jA = nA - iA * TS;
        dA[c] = (dir == 0) ? (jA * CSTRIDE + iA) : (iA * CSTRIDE + jA);
        cA[c] = (jA < 4) ? LOG2E : 0.0f;
        if (lane < 36) {
            int nB = 256 + 4 * lane + c;             // < 400
            int iB = nB / TS, jB = nB - iB * TS;
            dB[c] = (dir == 0) ? (jB * CSTRIDE + iB) : (iB * CSTRIDE + jB);
            cB[c] = (jB < 4) ? LOG2E : 0.0f;
        } else {
            dB[c] = 720 + (lane - 36) * 4 + c;       // private dump slot
            cB[c] = 0.0f;
        }
    }

    #define STAGE_TILE(dst, A, B)                                                \
        do {                                                                     \
            (dst)[dA[0]] = __builtin_amdgcn_exp2f(fmaf((A)[0], LOG2E, cA[0]));   \
            (dst)[dA[1]] = __builtin_amdgcn_exp2f(fmaf((A)[1], LOG2E, cA[1]));   \
            (dst)[dA[2]] = __builtin_amdgcn_exp2f(fmaf((A)[2], LOG2E, cA[2]));   \
            (dst)[dA[3]] = __builtin_amdgcn_exp2f(fmaf((A)[3], LOG2E, cA[3]));   \
            (dst)[dB[0]] = __builtin_amdgcn_exp2f(fmaf((B)[0], LOG2E, cB[0]));   \
            (dst)[dB[1]] = __builtin_amdgcn_exp2f(fmaf((B)[1], LOG2E, cB[1]));   \
            (dst)[dB[2]] = __builtin_amdgcn_exp2f(fmaf((B)[2], LOG2E, cB[2]));   \
            (dst)[dB[3]] = __builtin_amdgcn_exp2f(fmaf((B)[3], LOG2E, cB[3]));   \
        } while (0)

    const int S = (dir == 0) ? (min(len, HALF) - 1) : max(len - HALF, 0);

    if (S > 0) {
        // tile t <-> trellis row: fwd 1+t, bwd len-1-t
        #define LROW(t) ((dir == 0) ? (1 + (t)) : (len - 1 - (t)))
        f32x4 A0, B0, A1, B1, A2, B2, A3, B3, A4, B4, A5, B5;
        W5 wa, wb;

        // asm loads: defs are pinned at issue site — scheduler cannot sink them.
        #define LOAD_TILE(t, A, B)                                               \
            do {                                                                 \
                int row_ = LROW(min((t), S - 1));                                \
                const float* rp_ = trb + (size_t)row_ * LSTRIDE;                 \
                unsigned long long aA_ = (unsigned long long)(rp_ + 4 * lane);   \
                unsigned long long aB_ = (unsigned long long)(rp_ + 4 * fB);     \
                asm volatile("global_load_dwordx4 %0, %1, off"                   \
                             : "=v"(A) : "v"(aA_));                              \
                asm volatile("global_load_dwordx4 %0, %1, off"                   \
                             : "=v"(B) : "v"(aB_));                              \
            } while (0)

        LOAD_TILE(0, A0, B0);
        LOAD_TILE(1, A1, B1);
        LOAD_TILE(2, A2, B2);
        LOAD_TILE(3, A3, B3);
        LOAD_TILE(4, A4, B4);
        LOAD_TILE(5, A5, B5);
        // 12 outstanding; wait to 10 -> tile 0 complete
        asm volatile("s_waitcnt vmcnt(10)" : "+v"(A0), "+v"(B0));
        STAGE_TILE(&cbuf[0][0], A0, B0);
        {   // prefill current-w set from tile 0
            const f32x4* rp_ = (const f32x4*)&cbuf[0][jcs];
            wa.r0 = rp_[0]; wa.r1 = rp_[1]; wa.r2 = rp_[2]; wa.r3 = rp_[3]; wa.r4 = rp_[4];
        }

        // step U: load tile U+6; wait; stage tile U+1; prefetch w(U+1); matvec w(U)
        #define STEP(U, LA, LB, SA, SB, WB, WC, WN, RENORM)                      \
        {                                                                        \
            LOAD_TILE((U) + 6, LA, LB);                                          \
            asm volatile("s_waitcnt vmcnt(10)" : "+v"(SA), "+v"(SB));            \
            STAGE_TILE(&cbuf[WB][0], SA, SB);                                    \
            {                                                                    \
                const f32x4* rp_ = (const f32x4*)&cbuf[WB][jcs];                 \
                WN.r0 = rp_[0]; WN.r1 = rp_[1]; WN.r2 = rp_[2];                  \
                WN.r3 = rp_[3]; WN.r4 = rp_[4];                                  \
            }                                                                    \
            float a0 = qs[0] * WC.r0[0];                                         \
            float a1 = qs[1] * WC.r0[1];                                         \
            float a2 = qs[2] * WC.r0[2];                                         \
            float a3 = qs[3] * WC.r0[3];                                         \
            a0 = fmaf(qs[4],  WC.r1[0], a0);  a1 = fmaf(qs[5],  WC.r1[1], a1);   \
            a2 = fmaf(qs[6],  WC.r1[2], a2);  a3 = fmaf(qs[7],  WC.r1[3], a3);   \
            a0 = fmaf(qs[8],  WC.r2[0], a0);  a1 = fmaf(qs[9],  WC.r2[1], a1);   \
            a2 = fmaf(qs[10], WC.r2[2], a2);  a3 = fmaf(qs[11], WC.r2[3], a3);   \
            a0 = fmaf(qs[12], WC.r3[0], a0);  a1 = fmaf(qs[13], WC.r3[1], a1);   \
            a2 = fmaf(qs[14], WC.r3[2], a2);  a3 = fmaf(qs[15], WC.r3[3], a3);   \
            a0 = fmaf(qs[16], WC.r4[0], a0);  a1 = fmaf(qs[17], WC.r4[1], a1);   \
            a2 = fmaf(qs[18], WC.r4[2], a2);  a3 = fmaf(qs[19], WC.r4[3], a3);   \
            float acc = (a0 + a1) + (a2 + a3);                                   \
            q = ((U) < S) ? acc : q;        /* predicated, no branch */          \
            if (RENORM) {                   /* every 6 steps; range <= ~1e30 */  \
                int eb_ = __builtin_amdgcn_readfirstlane(__float_as_int(q));     \
                int e_ = ((eb_ >> 23) & 255) - 127;                              \
                s = fmaf((float)e_, LN2, s);                                     \
                q = q * __int_as_float((127 - e_) << 23);   /* * 2^-e exactly */ \
            }                                                                    \
            _Pragma("unroll")                                                    \
            for (int i = 0; i < TS; ++i)                                         \
                qs[i] = __int_as_float(                                          \
                    __builtin_amdgcn_readlane(__float_as_int(q), i));            \
        }

        const int nsteps = ((S + 5) / 6) * 6;
        for (int u = 0; u < nsteps; u += 6) {
            STEP(u + 0, A0, B0, A1, B1, 1, wa, wb, 0);
            STEP(u + 1, A1, B1, A2, B2, 0, wb, wa, 0);
            STEP(u + 2, A2, B2, A3, B3, 1, wa, wb, 0);
            STEP(u + 3, A3, B3, A4, B4, 0, wb, wa, 0);
            STEP(u + 4, A4, B4, A5, B5, 1, wa, wb, 0);
            STEP(u + 5, A5, B5, A0, B0, 0, wb, wa, 1);
        }
        #undef STEP
        #undef LOAD_TILE
        #undef LROW
    }

    float lq = __logf(q);

    float* ss = wsf + ((dir == 0) ? WS_FS : WS_BS);
    float* ll = wsf + ((dir == 0) ? WS_FL : WS_BL);
    if (lane == 0) ss[b] = s;
    if (lane < TS) ll[b * TS + lane] = lq;
}

// --- merge fwd x bwd, subtract gold, write loss ------------------------------
__global__ __launch_bounds__(128) void crf_merge(const float* __restrict__ wsf,
                                                 float* __restrict__ out) {
    const int b = threadIdx.x;   // 128 threads = 128 batches
    const float* fl = wsf + WS_FL + b * TS;
    const float* bl = wsf + WS_BL + b * TS;
    float v[TS];
    float m = -3e38f;
    #pragma unroll
    for (int i = 0; i < TS; ++i) { v[i] = fl[i] + bl[i]; m = fmaxf(m, v[i]); }
    float sum = 0.0f;
    #pragma unroll
    for (int i = 0; i < TS; ++i) sum += __expf(v[i] - m);
    float part = wsf[WS_FS + b] + wsf[WS_BS + b] + m + __logf(sum);
    #pragma unroll
    for (int off = 32; off; off >>= 1) part += __shfl_down(part, off);
    __shared__ float ps[2];
    if ((threadIdx.x & 63) == 0) ps[threadIdx.x >> 6] = part;
    __syncthreads();
    if (threadIdx.x == 0) out[0] = (ps[0] + ps[1] - wsf[WS_GOLD]) / 128.0f;
}

extern "C" void kernel_launch(void* const* d_in, const int* in_sizes, int n_in,
                              void* d_out, int out_size, void* d_ws, size_t ws_size,
                              hipStream_t stream) {
    const float* tr = (const float*)d_in[0];
    const int* gold32 = (const int*)d_in[1];
    const unsigned char* mask8 = (const unsigned char*)d_in[2];
    const int* mask32 = (const int*)d_in[2];
    float* wsf = (float*)d_ws;
    float* out = (float*)d_out;

    hipMemsetAsync(d_ws, 0, 64, stream);   // zero gold accumulator
    crf_chain<<<512, 64, 0, stream>>>(tr, mask8, mask32, gold32, wsf);
    crf_merge<<<1, 128, 0, stream>>>(wsf, out);
}